// Round 2
// baseline (559.431 us; speedup 1.0000x reference)
//
#include <hip/hip_runtime.h>
#include <hip/hip_bf16.h>

#define D_MODEL 1024
#define SEQ     2048
#define BATCH   2
#define NH      16
#define HD      64
#define MROWS   (BATCH*SEQ)   // 4096
#define XN      (MROWS*D_MODEL)      // 4194304
#define WN      (D_MODEL*D_MODEL)    // 1048576

typedef __attribute__((ext_vector_type(8))) __bf16 bf16x8;
typedef __attribute__((ext_vector_type(4))) __bf16 bf16x4;
typedef __attribute__((ext_vector_type(4))) float  floatx4;

#define MFMA(a,b,c) __builtin_amdgcn_mfma_f32_16x16x32_bf16((a),(b),(c),0,0,0)

// ---------------------------------------------------------------------------
// Kernel 0: convert f32 inputs -> bf16 staging in ws.
//   blockIdx.y: 0=x, 1=Wq, 2=Wk, 3=Wv, 4=Wo
// ---------------------------------------------------------------------------
__global__ __launch_bounds__(256) void cvt_kernel(
    const float* __restrict__ x,  const float* __restrict__ wq,
    const float* __restrict__ wk, const float* __restrict__ wv,
    const float* __restrict__ wo, __bf16* __restrict__ ws)
{
    const int y = blockIdx.y;
    const float* src;
    __bf16* dst;
    int n;
    if (y == 0) { src = x; dst = ws; n = XN; }
    else {
        n = WN;
        src = (y == 1) ? wq : (y == 2) ? wk : (y == 3) ? wv : wo;
        dst = ws + XN + (y - 1) * WN;
    }
    const int i = (blockIdx.x * 256 + threadIdx.x) * 4;
    if (i < n) {
        float4 f = *(const float4*)(src + i);
        bf16x4 o;
        o[0] = (__bf16)f.x; o[1] = (__bf16)f.y;
        o[2] = (__bf16)f.z; o[3] = (__bf16)f.w;
        *(bf16x4*)(dst + i) = o;
    }
}

// ---------------------------------------------------------------------------
// Kernel 1: QKV projection (C = X * W^T) + fused RoPE on Q,K.
//   which = blockIdx.z: 0=Q, 1=K, 2=V
//   Q -> q_ws (bf16);  K -> k_out (f32) + k_bf (bf16);
//   V -> v_out (f32) + vT_ws (bf16, [b][h][d][s])
// MFMA 16x16x32 bf16. A-frag: lane holds A[m=lane&15][k=quad*8+j]. B-frag:
// lane holds B[k=quad*8+j][n=lane&15] = W[n][k]. C/D: col=lane&15,
// row=quad*4+reg.
// ---------------------------------------------------------------------------
__global__ __launch_bounds__(256) void qkv_rope_kernel(
    const __bf16* __restrict__ x,  const __bf16* __restrict__ Wq,
    const __bf16* __restrict__ Wk, const __bf16* __restrict__ Wv,
    __bf16* __restrict__ q_ws, __bf16* __restrict__ k_bf,
    __bf16* __restrict__ vT_ws,
    float* __restrict__ k_out, float* __restrict__ v_out)
{
    const int which = blockIdx.z;
    const __bf16* W = (which == 0) ? Wq : (which == 1) ? Wk : Wv;
    const int m0   = blockIdx.x * 64;
    const int n0   = blockIdx.y * 64;
    const int wave = threadIdx.x >> 6;
    const int lane = threadIdx.x & 63;
    const int quad = lane >> 4;
    const int ln   = lane & 15;
    const int wm   = m0 + ((wave >> 1) << 5);   // wave's 32-row base
    const int wn   = n0 + ((wave & 1) << 5);    // wave's 32-col base

    const floatx4 fzero = {0.f, 0.f, 0.f, 0.f};
    floatx4 acc[2][2];
    acc[0][0] = fzero; acc[0][1] = fzero; acc[1][0] = fzero; acc[1][1] = fzero;

    const __bf16* xA0 = x + (wm + ln) * D_MODEL + quad * 8;
    const __bf16* xA1 = xA0 + 16 * D_MODEL;
    const __bf16* wB0 = W + (wn + ln) * D_MODEL + quad * 8;
    const __bf16* wB1 = wB0 + 16 * D_MODEL;

    for (int kk = 0; kk < D_MODEL; kk += 32) {
        bf16x8 a0 = *(const bf16x8*)(xA0 + kk);
        bf16x8 a1 = *(const bf16x8*)(xA1 + kk);
        bf16x8 b0 = *(const bf16x8*)(wB0 + kk);
        bf16x8 b1 = *(const bf16x8*)(wB1 + kk);
        acc[0][0] = MFMA(a0, b0, acc[0][0]);
        acc[0][1] = MFMA(a0, b1, acc[0][1]);
        acc[1][0] = MFMA(a1, b0, acc[1][0]);
        acc[1][1] = MFMA(a1, b1, acc[1][1]);
    }

    // epilogue: RoPE (Q,K) + scatter stores
    for (int mt = 0; mt < 2; ++mt) {
        for (int nt = 0; nt < 2; ++nt) {
            floatx4 c = acc[mt][nt];
            const int e = wn + nt * 16 + ln;   // output feature
            const int h = e >> 6;
            const int d = e & 63;
            if (which < 2) {
                // RoPE pairs (2i,2i+1); angle = s * base^(-2i/64). Feature
                // parity == lane parity, pair sits in adjacent lanes.
                const int   d2  = d & ~1;
                const float inv = exp2f(-(float)d2 * 0.20762050593046014f); // log2(1e4)/64
                for (int r = 0; r < 4; ++r) {
                    const int m = wm + mt * 16 + quad * 4 + r;
                    const int s = m & (SEQ - 1);
                    float self  = c[r];
                    float other = __shfl_xor(self, 1);
                    float ang = (float)s * inv;
                    float sn, cs;
                    sincosf(ang, &sn, &cs);
                    c[r] = (lane & 1) ? (other * sn + self * cs)
                                      : (self * cs - other * sn);
                }
            }
            for (int r = 0; r < 4; ++r) {
                const int m = wm + mt * 16 + quad * 4 + r;
                const int b = m >> 11;            // / SEQ
                const int s = m & (SEQ - 1);
                const int idx = ((b * NH + h) * SEQ + s) * HD + d;
                if (which == 0) {
                    q_ws[idx] = (__bf16)c[r];
                } else if (which == 1) {
                    k_out[idx] = c[r];
                    k_bf[idx]  = (__bf16)c[r];
                } else {
                    v_out[idx] = c[r];
                }
            }
            if (which == 2) {
                // V transposed [b][h][d][s] (bf16), 4 consecutive s per lane
                const int mq = wm + mt * 16 + quad * 4;
                const int b  = mq >> 11;
                const int s  = mq & (SEQ - 1);
                bf16x4 pk;
                pk[0] = (__bf16)c[0]; pk[1] = (__bf16)c[1];
                pk[2] = (__bf16)c[2]; pk[3] = (__bf16)c[3];
                *(bf16x4*)(vT_ws + ((b * NH + h) * HD + d) * SEQ + s) = pk;
            }
        }
    }
}

// ---------------------------------------------------------------------------
// Kernel 2: causal flash attention. One wave per (b,h, 16-row Qtile).
// K-tiles of 32 keys: QK^T via 4 MFMAs; online softmax (16-lane shuffles);
// P C-layout -> LDS -> A-layout; PV via 4 MFMAs against V^T fragments.
// ---------------------------------------------------------------------------
__global__ __launch_bounds__(64) void attn_kernel(
    const __bf16* __restrict__ q_ws, const __bf16* __restrict__ k_all,
    const __bf16* __restrict__ vT,   __bf16* __restrict__ attn_ws)
{
    const int t    = blockIdx.x;
    const int bh   = t >> 7;            // / (SEQ/16)
    const int i0   = (t & 127) << 4;
    const int lane = threadIdx.x & 63;
    const int quad = lane >> 4;
    const int ln   = lane & 15;

    const __bf16* qb = q_ws + bh * SEQ * HD;
    const __bf16* kb = k_all + bh * SEQ * HD;
    const __bf16* vb = vT + bh * HD * SEQ;

    const bf16x8 aq0 = *(const bf16x8*)(qb + (i0 + ln) * HD + quad * 8);
    const bf16x8 aq1 = *(const bf16x8*)(qb + (i0 + ln) * HD + 32 + quad * 8);

    const floatx4 fzero = {0.f, 0.f, 0.f, 0.f};
    floatx4 acc[4];
    acc[0] = fzero; acc[1] = fzero; acc[2] = fzero; acc[3] = fzero;
    float m_i[4] = {-1e30f, -1e30f, -1e30f, -1e30f};
    float l_i[4] = {0.f, 0.f, 0.f, 0.f};

    // P tile 16x32, row stride 40 bf16 (80 B rows -> 16B-aligned)
    __shared__ __align__(16) __bf16 lds_p[16 * 40];

    const int ntiles = (i0 + 47) >> 5;   // ceil((i0+16)/32)
    for (int tk = 0; tk < ntiles; ++tk) {
        const int j0 = tk << 5;
        bf16x8 bk00 = *(const bf16x8*)(kb + (j0 + ln) * HD + quad * 8);
        bf16x8 bk01 = *(const bf16x8*)(kb + (j0 + ln) * HD + 32 + quad * 8);
        bf16x8 bk10 = *(const bf16x8*)(kb + (j0 + 16 + ln) * HD + quad * 8);
        bf16x8 bk11 = *(const bf16x8*)(kb + (j0 + 16 + ln) * HD + 32 + quad * 8);
        floatx4 s0 = fzero, s1 = fzero;
        s0 = MFMA(aq0, bk00, s0);
        s0 = MFMA(aq1, bk01, s0);
        s1 = MFMA(aq0, bk10, s1);
        s1 = MFMA(aq1, bk11, s1);

        for (int r = 0; r < 4; ++r) { s0[r] *= 0.125f; s1[r] *= 0.125f; }
        if (j0 + 31 > i0) {   // tile touches the diagonal -> causal mask
            for (int r = 0; r < 4; ++r) {
                const int row = i0 + quad * 4 + r;
                if (j0 + ln > row)      s0[r] = -1e30f;
                if (j0 + 16 + ln > row) s1[r] = -1e30f;
            }
        }

        float alpha[4], mnew[4];
        for (int r = 0; r < 4; ++r) {
            float v = fmaxf(s0[r], s1[r]);
            v = fmaxf(v, __shfl_xor(v, 1));
            v = fmaxf(v, __shfl_xor(v, 2));
            v = fmaxf(v, __shfl_xor(v, 4));
            v = fmaxf(v, __shfl_xor(v, 8));
            float mn = fmaxf(m_i[r], v);
            alpha[r] = __expf(fminf(m_i[r] - mn, 0.f));
            m_i[r] = mn;
            mnew[r] = mn;
        }
        floatx4 p0, p1;
        for (int r = 0; r < 4; ++r) {
            p0[r] = __expf(fminf(s0[r] - mnew[r], 0.f));
            p1[r] = __expf(fminf(s1[r] - mnew[r], 0.f));
        }
        for (int r = 0; r < 4; ++r) {
            float v = p0[r] + p1[r];
            v += __shfl_xor(v, 1);
            v += __shfl_xor(v, 2);
            v += __shfl_xor(v, 4);
            v += __shfl_xor(v, 8);
            l_i[r] = l_i[r] * alpha[r] + v;
        }
        for (int n = 0; n < 4; ++n)
            for (int r = 0; r < 4; ++r)
                acc[n][r] *= alpha[r];

        // P: C-layout -> LDS -> A-layout (bf16)
        for (int r = 0; r < 4; ++r) {
            lds_p[(quad * 4 + r) * 40 + ln]      = (__bf16)p0[r];
            lds_p[(quad * 4 + r) * 40 + 16 + ln] = (__bf16)p1[r];
        }
        __syncthreads();
        bf16x8 ap = *(const bf16x8*)(lds_p + ln * 40 + quad * 8);
        __syncthreads();

        bf16x8 bv0 = *(const bf16x8*)(vb + (ln)      * SEQ + j0 + quad * 8);
        bf16x8 bv1 = *(const bf16x8*)(vb + (16 + ln) * SEQ + j0 + quad * 8);
        bf16x8 bv2 = *(const bf16x8*)(vb + (32 + ln) * SEQ + j0 + quad * 8);
        bf16x8 bv3 = *(const bf16x8*)(vb + (48 + ln) * SEQ + j0 + quad * 8);
        acc[0] = MFMA(ap, bv0, acc[0]);
        acc[1] = MFMA(ap, bv1, acc[1]);
        acc[2] = MFMA(ap, bv2, acc[2]);
        acc[3] = MFMA(ap, bv3, acc[3]);
    }

    const int b = bh >> 4, h = bh & 15;
    for (int r = 0; r < 4; ++r) {
        const float inv = 1.f / fmaxf(l_i[r], 1e-30f);
        const int s = i0 + quad * 4 + r;
        for (int n = 0; n < 4; ++n) {
            attn_ws[(b * SEQ + s) * D_MODEL + h * HD + n * 16 + ln] =
                (__bf16)(acc[n][r] * inv);
        }
    }
}

// ---------------------------------------------------------------------------
// Kernel 3: output projection  out = attn * Wo^T  (f32 out)
// ---------------------------------------------------------------------------
__global__ __launch_bounds__(256) void out_proj_kernel(
    const __bf16* __restrict__ A, const __bf16* __restrict__ Wo,
    float* __restrict__ out)
{
    const int m0   = blockIdx.x * 64;
    const int n0   = blockIdx.y * 64;
    const int wave = threadIdx.x >> 6;
    const int lane = threadIdx.x & 63;
    const int quad = lane >> 4;
    const int ln   = lane & 15;
    const int wm   = m0 + ((wave >> 1) << 5);
    const int wn   = n0 + ((wave & 1) << 5);

    const floatx4 fzero = {0.f, 0.f, 0.f, 0.f};
    floatx4 acc[2][2];
    acc[0][0] = fzero; acc[0][1] = fzero; acc[1][0] = fzero; acc[1][1] = fzero;

    const __bf16* xA0 = A + (wm + ln) * D_MODEL + quad * 8;
    const __bf16* xA1 = xA0 + 16 * D_MODEL;
    const __bf16* wB0 = Wo + (wn + ln) * D_MODEL + quad * 8;
    const __bf16* wB1 = wB0 + 16 * D_MODEL;

    for (int kk = 0; kk < D_MODEL; kk += 32) {
        bf16x8 a0 = *(const bf16x8*)(xA0 + kk);
        bf16x8 a1 = *(const bf16x8*)(xA1 + kk);
        bf16x8 b0 = *(const bf16x8*)(wB0 + kk);
        bf16x8 b1 = *(const bf16x8*)(wB1 + kk);
        acc[0][0] = MFMA(a0, b0, acc[0][0]);
        acc[0][1] = MFMA(a0, b1, acc[0][1]);
        acc[1][0] = MFMA(a1, b0, acc[1][0]);
        acc[1][1] = MFMA(a1, b1, acc[1][1]);
    }

    for (int mt = 0; mt < 2; ++mt) {
        for (int nt = 0; nt < 2; ++nt) {
            const floatx4 c = acc[mt][nt];
            const int e = wn + nt * 16 + ln;
            for (int r = 0; r < 4; ++r) {
                const int m = wm + mt * 16 + quad * 4 + r;
                out[m * D_MODEL + e] = c[r];
            }
        }
    }
}

// ---------------------------------------------------------------------------
extern "C" void kernel_launch(void* const* d_in, const int* in_sizes, int n_in,
                              void* d_out, int out_size, void* d_ws, size_t ws_size,
                              hipStream_t stream)
{
    (void)in_sizes; (void)n_in; (void)out_size; (void)ws_size;
    const float* x  = (const float*)d_in[0];
    // d_in[1] = mask (causal triu, k=1) — implemented analytically, not read
    const float* Wq = (const float*)d_in[2];
    const float* Wk = (const float*)d_in[3];
    const float* Wv = (const float*)d_in[4];
    const float* Wo = (const float*)d_in[5];

    float* out   = (float*)d_out;           // [B,S,D]
    float* k_out = out + XN;                // [B,H,S,hd]
    float* v_out = k_out + XN;              // [B,H,S,hd]

    __bf16* ws      = (__bf16*)d_ws;
    __bf16* x_bf    = ws;                   // XN
    __bf16* Wq_bf   = ws + XN;              // WN
    __bf16* Wk_bf   = Wq_bf + WN;
    __bf16* Wv_bf   = Wk_bf + WN;
    __bf16* Wo_bf   = Wv_bf + WN;
    __bf16* q_ws    = Wo_bf + WN;           // XN  [B,H,S,hd]
    __bf16* k_bf    = q_ws + XN;            // XN  [B,H,S,hd]
    __bf16* vT_ws   = k_bf + XN;            // XN  [B,H,hd,S]
    __bf16* attn_ws = vT_ws + XN;           // XN  [B,S,D]

    dim3 gc(XN / 4 / 256, 5);
    cvt_kernel<<<gc, 256, 0, stream>>>(x, Wq, Wk, Wv, Wo, ws);

    dim3 g1(MROWS / 64, D_MODEL / 64, 3);
    qkv_rope_kernel<<<g1, 256, 0, stream>>>(x_bf, Wq_bf, Wk_bf, Wv_bf,
                                            q_ws, k_bf, vT_ws, k_out, v_out);

    dim3 g2(BATCH * NH * (SEQ / 16));
    attn_kernel<<<g2, 64, 0, stream>>>(q_ws, k_bf, vT_ws, attn_ws);

    dim3 g3(MROWS / 64, D_MODEL / 64);
    out_proj_kernel<<<g3, 256, 0, stream>>>(attn_ws, Wo_bf, out);
}

// Round 3
// 465.574 us; speedup vs baseline: 1.2016x; 1.2016x over previous
//
#include <hip/hip_runtime.h>
#include <hip/hip_bf16.h>

#define D_MODEL 1024
#define SEQ     2048
#define BATCH   2
#define NH      16
#define HD      64
#define MROWS   (BATCH*SEQ)   // 4096
#define XN      (MROWS*D_MODEL)      // 4194304
#define WN      (D_MODEL*D_MODEL)    // 1048576

typedef __attribute__((ext_vector_type(8))) __bf16 bf16x8;
typedef __attribute__((ext_vector_type(4))) __bf16 bf16x4;
typedef __attribute__((ext_vector_type(4))) float  floatx4;

#define MFMA(a,b,c) __builtin_amdgcn_mfma_f32_16x16x32_bf16((a),(b),(c),0,0,0)

// ---------------------------------------------------------------------------
// Kernel 0: convert f32 inputs -> bf16 staging in ws.
// ---------------------------------------------------------------------------
__global__ __launch_bounds__(256) void cvt_kernel(
    const float* __restrict__ x,  const float* __restrict__ wq,
    const float* __restrict__ wk, const float* __restrict__ wv,
    const float* __restrict__ wo, __bf16* __restrict__ ws)
{
    const int y = blockIdx.y;
    const float* src;
    __bf16* dst;
    int n;
    if (y == 0) { src = x; dst = ws; n = XN; }
    else {
        n = WN;
        src = (y == 1) ? wq : (y == 2) ? wk : (y == 3) ? wv : wo;
        dst = ws + XN + (y - 1) * WN;
    }
    const int i = (blockIdx.x * 256 + threadIdx.x) * 4;
    if (i < n) {
        float4 f = *(const float4*)(src + i);
        bf16x4 o;
        o[0] = (__bf16)f.x; o[1] = (__bf16)f.y;
        o[2] = (__bf16)f.z; o[3] = (__bf16)f.w;
        *(bf16x4*)(dst + i) = o;
    }
}

// ---------------------------------------------------------------------------
// Kernel 1: QKV projection (C = X * W^T) + fused RoPE on Q,K. (unchanged)
// ---------------------------------------------------------------------------
__global__ __launch_bounds__(256) void qkv_rope_kernel(
    const __bf16* __restrict__ x,  const __bf16* __restrict__ Wq,
    const __bf16* __restrict__ Wk, const __bf16* __restrict__ Wv,
    __bf16* __restrict__ q_ws, __bf16* __restrict__ k_bf,
    __bf16* __restrict__ vT_ws,
    float* __restrict__ k_out, float* __restrict__ v_out)
{
    const int which = blockIdx.z;
    const __bf16* W = (which == 0) ? Wq : (which == 1) ? Wk : Wv;
    const int m0   = blockIdx.x * 64;
    const int n0   = blockIdx.y * 64;
    const int wave = threadIdx.x >> 6;
    const int lane = threadIdx.x & 63;
    const int quad = lane >> 4;
    const int ln   = lane & 15;
    const int wm   = m0 + ((wave >> 1) << 5);
    const int wn   = n0 + ((wave & 1) << 5);

    const floatx4 fzero = {0.f, 0.f, 0.f, 0.f};
    floatx4 acc[2][2];
    acc[0][0] = fzero; acc[0][1] = fzero; acc[1][0] = fzero; acc[1][1] = fzero;

    const __bf16* xA0 = x + (wm + ln) * D_MODEL + quad * 8;
    const __bf16* xA1 = xA0 + 16 * D_MODEL;
    const __bf16* wB0 = W + (wn + ln) * D_MODEL + quad * 8;
    const __bf16* wB1 = wB0 + 16 * D_MODEL;

    for (int kk = 0; kk < D_MODEL; kk += 32) {
        bf16x8 a0 = *(const bf16x8*)(xA0 + kk);
        bf16x8 a1 = *(const bf16x8*)(xA1 + kk);
        bf16x8 b0 = *(const bf16x8*)(wB0 + kk);
        bf16x8 b1 = *(const bf16x8*)(wB1 + kk);
        acc[0][0] = MFMA(a0, b0, acc[0][0]);
        acc[0][1] = MFMA(a0, b1, acc[0][1]);
        acc[1][0] = MFMA(a1, b0, acc[1][0]);
        acc[1][1] = MFMA(a1, b1, acc[1][1]);
    }

    for (int mt = 0; mt < 2; ++mt) {
        for (int nt = 0; nt < 2; ++nt) {
            floatx4 c = acc[mt][nt];
            const int e = wn + nt * 16 + ln;
            const int h = e >> 6;
            const int d = e & 63;
            if (which < 2) {
                const int   d2  = d & ~1;
                const float inv = exp2f(-(float)d2 * 0.20762050593046014f);
                for (int r = 0; r < 4; ++r) {
                    const int m = wm + mt * 16 + quad * 4 + r;
                    const int s = m & (SEQ - 1);
                    float self  = c[r];
                    float other = __shfl_xor(self, 1);
                    float ang = (float)s * inv;
                    float sn, cs;
                    sincosf(ang, &sn, &cs);
                    c[r] = (lane & 1) ? (other * sn + self * cs)
                                      : (self * cs - other * sn);
                }
            }
            for (int r = 0; r < 4; ++r) {
                const int m = wm + mt * 16 + quad * 4 + r;
                const int b = m >> 11;
                const int s = m & (SEQ - 1);
                const int idx = ((b * NH + h) * SEQ + s) * HD + d;
                if (which == 0) {
                    q_ws[idx] = (__bf16)c[r];
                } else if (which == 1) {
                    k_out[idx] = c[r];
                    k_bf[idx]  = (__bf16)c[r];
                } else {
                    v_out[idx] = c[r];
                }
            }
            if (which == 2) {
                const int mq = wm + mt * 16 + quad * 4;
                const int b  = mq >> 11;
                const int s  = mq & (SEQ - 1);
                bf16x4 pk;
                pk[0] = (__bf16)c[0]; pk[1] = (__bf16)c[1];
                pk[2] = (__bf16)c[2]; pk[3] = (__bf16)c[3];
                *(bf16x4*)(vT_ws + ((b * NH + h) * HD + d) * SEQ + s) = pk;
            }
        }
    }
}

// ---------------------------------------------------------------------------
// Kernel 2: causal flash attention, restructured.
// Block = 256 thr = 4 independent waves. Block covers 64 Q-rows; wave w owns
// rows [qt*64+16w, +16). BN=64 keys/iter: QK = 8 MFMAs, PV = 8 MFMAs.
// K fragments software-pipelined across iterations (next-tile loads issued
// right after current QK consumes the regs); V loads issued at iter top,
// consumed at iter bottom. P transposes C-layout -> A-layout through a
// PRIVATE per-wave LDS slice (stride 72 -> 2-way bank aliasing = free); no
// __syncthreads anywhere. Scale 1/8 folded into exp-fma (max reduced on raw
// scores: monotone). Blocks ordered heaviest-first (qt descending) for
// causal load balance; 4 waves of a block sit on adjacent row-tiles.
// ---------------------------------------------------------------------------
__global__ __launch_bounds__(256) void attn_kernel(
    const __bf16* __restrict__ q_ws, const __bf16* __restrict__ k_all,
    const __bf16* __restrict__ vT,   __bf16* __restrict__ attn_ws)
{
    const int bh   = blockIdx.x & 31;          // (b,h) pair
    const int qt   = 31 - (blockIdx.x >> 5);   // 64-row Q-tile, heavy first
    const int w    = threadIdx.x >> 6;
    const int lane = threadIdx.x & 63;
    const int quad = lane >> 4;
    const int ln   = lane & 15;
    const int r0   = qt * 64 + w * 16;

    const __bf16* qb = q_ws + bh * SEQ * HD;
    const __bf16* kb = k_all + bh * SEQ * HD;
    const __bf16* vb = vT + bh * HD * SEQ;

    // Q A-fragments (rows r0+ln, k-chunks 0/1)
    const bf16x8 aq0 = *(const bf16x8*)(qb + (r0 + ln) * HD + quad * 8);
    const bf16x8 aq1 = *(const bf16x8*)(qb + (r0 + ln) * HD + 32 + quad * 8);

    floatx4 acc[4] = {};                 // O tile 16x64, C-layout
    float m_i[4] = {-1e30f, -1e30f, -1e30f, -1e30f};
    float l_i[4] = {0.f, 0.f, 0.f, 0.f};

    // per-wave private LDS: P tile 16 rows x stride 72 bf16 (144 B rows)
    __shared__ __align__(16) __bf16 ldsp[4][16 * 72];
    __bf16* lp = &ldsp[w][0];

    // K B-frag base: key = j0 + nt*16 + ln, bytes quad*16 + kc*64
    const __bf16* kbase = kb + ln * HD + quad * 8;
    const __bf16* vbase = vb + ln * SEQ + quad * 8;

    bf16x8 K[8];   // [nt][kc]
    #pragma unroll
    for (int nt = 0; nt < 4; ++nt)
        #pragma unroll
        for (int kc = 0; kc < 2; ++kc)
            K[nt * 2 + kc] = *(const bf16x8*)(kbase + nt * 16 * HD + kc * 32);

    const int nk = qt + 1;               // 64-key tiles to process
    for (int tk = 0; tk < nk; ++tk) {
        const int j0 = tk << 6;

        // V B-frags for this iter (consumed at iter bottom)
        bf16x8 V[8];   // [nt(hd)][kc(key)]
        #pragma unroll
        for (int nt = 0; nt < 4; ++nt)
            #pragma unroll
            for (int kc = 0; kc < 2; ++kc)
                V[nt * 2 + kc] =
                    *(const bf16x8*)(vbase + nt * 16 * SEQ + j0 + kc * 32);

        // QK^T: 16x64 raw scores
        floatx4 s[4] = {};
        #pragma unroll
        for (int nt = 0; nt < 4; ++nt) {
            s[nt] = MFMA(aq0, K[nt * 2 + 0], s[nt]);
            s[nt] = MFMA(aq1, K[nt * 2 + 1], s[nt]);
        }

        // prefetch next K-tile while softmax runs
        if (tk + 1 < nk) {
            const __bf16* kn = kbase + (j0 + 64) * HD;
            #pragma unroll
            for (int nt = 0; nt < 4; ++nt)
                #pragma unroll
                for (int kc = 0; kc < 2; ++kc)
                    K[nt * 2 + kc] =
                        *(const bf16x8*)(kn + nt * 16 * HD + kc * 32);
        }

        if (tk == nk - 1) {   // only the diagonal tile needs masking
            #pragma unroll
            for (int nt = 0; nt < 4; ++nt) {
                const int col = j0 + nt * 16 + ln;
                #pragma unroll
                for (int r = 0; r < 4; ++r)
                    if (col > r0 + quad * 4 + r) s[nt][r] = -1e30f;
            }
        }

        // online softmax (raw-score max; 1/8 scale folded into exp arg)
        float alpha[4], mnew[4];
        #pragma unroll
        for (int r = 0; r < 4; ++r) {
            float v = fmaxf(fmaxf(s[0][r], s[1][r]), fmaxf(s[2][r], s[3][r]));
            v = fmaxf(v, __shfl_xor(v, 1));
            v = fmaxf(v, __shfl_xor(v, 2));
            v = fmaxf(v, __shfl_xor(v, 4));
            v = fmaxf(v, __shfl_xor(v, 8));
            const float mn = fmaxf(m_i[r], v * 0.125f);
            alpha[r] = __expf(m_i[r] - mn);
            m_i[r] = mn;
            mnew[r] = mn;
        }
        floatx4 p[4];
        #pragma unroll
        for (int nt = 0; nt < 4; ++nt)
            #pragma unroll
            for (int r = 0; r < 4; ++r)
                p[nt][r] = __expf(fmaf(s[nt][r], 0.125f, -mnew[r]));
        #pragma unroll
        for (int r = 0; r < 4; ++r) {
            float v = (p[0][r] + p[1][r]) + (p[2][r] + p[3][r]);
            v += __shfl_xor(v, 1);
            v += __shfl_xor(v, 2);
            v += __shfl_xor(v, 4);
            v += __shfl_xor(v, 8);
            l_i[r] = l_i[r] * alpha[r] + v;
        }
        #pragma unroll
        for (int nt = 0; nt < 4; ++nt)
            #pragma unroll
            for (int r = 0; r < 4; ++r)
                acc[nt][r] *= alpha[r];

        // P: C-layout -> LDS -> A-layout (intra-wave, no barrier needed)
        #pragma unroll
        for (int nt = 0; nt < 4; ++nt)
            #pragma unroll
            for (int r = 0; r < 4; ++r)
                lp[(quad * 4 + r) * 72 + nt * 16 + ln] = (__bf16)p[nt][r];
        const bf16x8 ap0 = *(const bf16x8*)(lp + ln * 72 + quad * 8);
        const bf16x8 ap1 = *(const bf16x8*)(lp + ln * 72 + 32 + quad * 8);

        // PV
        #pragma unroll
        for (int nt = 0; nt < 4; ++nt) {
            acc[nt] = MFMA(ap0, V[nt * 2 + 0], acc[nt]);
            acc[nt] = MFMA(ap1, V[nt * 2 + 1], acc[nt]);
        }
    }

    const int b = bh >> 4, h = bh & 15;
    #pragma unroll
    for (int r = 0; r < 4; ++r) {
        const float inv = 1.f / fmaxf(l_i[r], 1e-30f);
        const int s = r0 + quad * 4 + r;
        #pragma unroll
        for (int nt = 0; nt < 4; ++nt) {
            attn_ws[(b * SEQ + s) * D_MODEL + h * HD + nt * 16 + ln] =
                (__bf16)(acc[nt][r] * inv);
        }
    }
}

// ---------------------------------------------------------------------------
// Kernel 3: output projection  out = attn * Wo^T  (f32 out, unchanged)
// ---------------------------------------------------------------------------
__global__ __launch_bounds__(256) void out_proj_kernel(
    const __bf16* __restrict__ A, const __bf16* __restrict__ Wo,
    float* __restrict__ out)
{
    const int m0   = blockIdx.x * 64;
    const int n0   = blockIdx.y * 64;
    const int wave = threadIdx.x >> 6;
    const int lane = threadIdx.x & 63;
    const int quad = lane >> 4;
    const int ln   = lane & 15;
    const int wm   = m0 + ((wave >> 1) << 5);
    const int wn   = n0 + ((wave & 1) << 5);

    const floatx4 fzero = {0.f, 0.f, 0.f, 0.f};
    floatx4 acc[2][2];
    acc[0][0] = fzero; acc[0][1] = fzero; acc[1][0] = fzero; acc[1][1] = fzero;

    const __bf16* xA0 = A + (wm + ln) * D_MODEL + quad * 8;
    const __bf16* xA1 = xA0 + 16 * D_MODEL;
    const __bf16* wB0 = Wo + (wn + ln) * D_MODEL + quad * 8;
    const __bf16* wB1 = wB0 + 16 * D_MODEL;

    for (int kk = 0; kk < D_MODEL; kk += 32) {
        bf16x8 a0 = *(const bf16x8*)(xA0 + kk);
        bf16x8 a1 = *(const bf16x8*)(xA1 + kk);
        bf16x8 b0 = *(const bf16x8*)(wB0 + kk);
        bf16x8 b1 = *(const bf16x8*)(wB1 + kk);
        acc[0][0] = MFMA(a0, b0, acc[0][0]);
        acc[0][1] = MFMA(a0, b1, acc[0][1]);
        acc[1][0] = MFMA(a1, b0, acc[1][0]);
        acc[1][1] = MFMA(a1, b1, acc[1][1]);
    }

    for (int mt = 0; mt < 2; ++mt) {
        for (int nt = 0; nt < 2; ++nt) {
            const floatx4 c = acc[mt][nt];
            const int e = wn + nt * 16 + ln;
            for (int r = 0; r < 4; ++r) {
                const int m = wm + mt * 16 + quad * 4 + r;
                out[m * D_MODEL + e] = c[r];
            }
        }
    }
}

// ---------------------------------------------------------------------------
extern "C" void kernel_launch(void* const* d_in, const int* in_sizes, int n_in,
                              void* d_out, int out_size, void* d_ws, size_t ws_size,
                              hipStream_t stream)
{
    (void)in_sizes; (void)n_in; (void)out_size; (void)ws_size;
    const float* x  = (const float*)d_in[0];
    // d_in[1] = mask — analytic causal mask, not read
    const float* Wq = (const float*)d_in[2];
    const float* Wk = (const float*)d_in[3];
    const float* Wv = (const float*)d_in[4];
    const float* Wo = (const float*)d_in[5];

    float* out   = (float*)d_out;           // [B,S,D]
    float* k_out = out + XN;                // [B,H,S,hd]
    float* v_out = k_out + XN;              // [B,H,S,hd]

    __bf16* ws      = (__bf16*)d_ws;
    __bf16* x_bf    = ws;                   // XN
    __bf16* Wq_bf   = ws + XN;              // WN
    __bf16* Wk_bf   = Wq_bf + WN;
    __bf16* Wv_bf   = Wk_bf + WN;
    __bf16* Wo_bf   = Wv_bf + WN;
    __bf16* q_ws    = Wo_bf + WN;           // XN  [B,H,S,hd]
    __bf16* k_bf    = q_ws + XN;            // XN  [B,H,S,hd]
    __bf16* vT_ws   = k_bf + XN;            // XN  [B,H,hd,S]
    __bf16* attn_ws = vT_ws + XN;           // XN  [B,S,D]

    dim3 gc(XN / 4 / 256, 5);
    cvt_kernel<<<gc, 256, 0, stream>>>(x, Wq, Wk, Wv, Wo, ws);

    dim3 g1(MROWS / 64, D_MODEL / 64, 3);
    qkv_rope_kernel<<<g1, 256, 0, stream>>>(x_bf, Wq_bf, Wk_bf, Wv_bf,
                                            q_ws, k_bf, vT_ws, k_out, v_out);

    attn_kernel<<<dim3(32 * 32), 256, 0, stream>>>(q_ws, k_bf, vT_ws, attn_ws);

    dim3 g3(MROWS / 64, D_MODEL / 64);
    out_proj_kernel<<<g3, 256, 0, stream>>>(attn_ws, Wo_bf, out);
}

// Round 4
// 334.532 us; speedup vs baseline: 1.6723x; 1.3917x over previous
//
#include <hip/hip_runtime.h>
#include <hip/hip_bf16.h>
#include <stdint.h>

#define D_MODEL 1024
#define SEQ     2048
#define BATCH   2
#define NH      16
#define HD      64
#define MROWS   (BATCH*SEQ)   // 4096
#define XN      (MROWS*D_MODEL)      // 4194304
#define WN      (D_MODEL*D_MODEL)    // 1048576

typedef __attribute__((ext_vector_type(8))) __bf16 bf16x8;
typedef __attribute__((ext_vector_type(4))) __bf16 bf16x4;
typedef __attribute__((ext_vector_type(4))) float  floatx4;

#define MFMA(a,b,c) __builtin_amdgcn_mfma_f32_16x16x32_bf16((a),(b),(c),0,0,0)

// async global->LDS, 16 B per lane; LDS dest is wave-uniform base + lane*16
__device__ __forceinline__ void g2l16(const void* g, void* l) {
    __builtin_amdgcn_global_load_lds(
        (const __attribute__((address_space(1))) void*)g,
        (__attribute__((address_space(3))) void*)l, 16, 0, 0);
}

// ---------------------------------------------------------------------------
// Kernel 0: convert f32 inputs -> bf16 staging in ws.
// ---------------------------------------------------------------------------
__global__ __launch_bounds__(256) void cvt_kernel(
    const float* __restrict__ x,  const float* __restrict__ wq,
    const float* __restrict__ wk, const float* __restrict__ wv,
    const float* __restrict__ wo, __bf16* __restrict__ ws)
{
    const int y = blockIdx.y;
    const float* src;
    __bf16* dst;
    int n;
    if (y == 0) { src = x; dst = ws; n = XN; }
    else {
        n = WN;
        src = (y == 1) ? wq : (y == 2) ? wk : (y == 3) ? wv : wo;
        dst = ws + XN + (y - 1) * WN;
    }
    const int i = (blockIdx.x * 256 + threadIdx.x) * 4;
    if (i < n) {
        float4 f = *(const float4*)(src + i);
        bf16x4 o;
        o[0] = (__bf16)f.x; o[1] = (__bf16)f.y;
        o[2] = (__bf16)f.z; o[3] = (__bf16)f.w;
        *(bf16x4*)(dst + i) = o;
    }
}

// ---------------------------------------------------------------------------
// m97-style 128x128 GEMM core (C = A * W^T), BK=32, 4 waves, 4x4 frags/wave.
// LDS tiles 128x32 bf16 row-major unpacked (64 B rows) — global_load_lds
// requires the packed lane-order layout (no padding); the b128 fragment
// reads then touch each bank exactly 8x (minimum for b128) = conflict-free.
// ---------------------------------------------------------------------------
__device__ __forceinline__ void gemm128_core(
    const __bf16* __restrict__ A, const __bf16* __restrict__ W,
    int m0, int n0, __bf16* ldsA, __bf16* ldsB, floatx4 acc[4][4])
{
    const int tid  = threadIdx.x;
    const int w    = tid >> 6;
    const int lane = tid & 63;
    const int quad = lane >> 4;
    const int ln   = lane & 15;
    const int wm   = (w >> 1) << 6;
    const int wn   = (w & 1) << 6;

    // staging source rows/chunks: idx = c*256 + tid; row=idx>>2, chunk=idx&3
    const int r0c = tid >> 2, ch = tid & 3;
    const __bf16* gA0 = A + (m0 + r0c) * D_MODEL + ch * 8;
    const __bf16* gA1 = gA0 + 64 * D_MODEL;
    const __bf16* gB0 = W + (n0 + r0c) * D_MODEL + ch * 8;
    const __bf16* gB1 = gB0 + 64 * D_MODEL;
    // wave-uniform LDS bases (elements): (c*256 + w*64) * 8
    __bf16* lA0 = ldsA + w * 512;
    __bf16* lA1 = ldsA + 2048 + w * 512;
    __bf16* lB0 = ldsB + w * 512;
    __bf16* lB1 = ldsB + 2048 + w * 512;

    for (int k0 = 0; k0 < D_MODEL; k0 += 32) {
        __syncthreads();                    // LDS safe to overwrite
        g2l16(gA0 + k0, lA0);
        g2l16(gA1 + k0, lA1);
        g2l16(gB0 + k0, lB0);
        g2l16(gB1 + k0, lB1);
        __syncthreads();                    // staging complete

        bf16x8 af[4], bf[4];
        #pragma unroll
        for (int mt = 0; mt < 4; ++mt)
            af[mt] = *(const bf16x8*)(ldsA + (wm + mt * 16 + ln) * 32 + quad * 8);
        #pragma unroll
        for (int nt = 0; nt < 4; ++nt)
            bf[nt] = *(const bf16x8*)(ldsB + (wn + nt * 16 + ln) * 32 + quad * 8);
        #pragma unroll
        for (int mt = 0; mt < 4; ++mt)
            #pragma unroll
            for (int nt = 0; nt < 4; ++nt)
                acc[mt][nt] = MFMA(af[mt], bf[nt], acc[mt][nt]);
    }
}

// ---------------------------------------------------------------------------
// Kernel 1: QKV projection (C = X * W^T) + fused RoPE on Q,K.
//   which = blockIdx.z: 0=Q, 1=K, 2=V
// ---------------------------------------------------------------------------
__global__ __launch_bounds__(256) void qkv_rope_kernel(
    const __bf16* __restrict__ x,  const __bf16* __restrict__ Wq,
    const __bf16* __restrict__ Wk, const __bf16* __restrict__ Wv,
    __bf16* __restrict__ q_ws, __bf16* __restrict__ k_bf,
    __bf16* __restrict__ vT_ws,
    float* __restrict__ k_out, float* __restrict__ v_out)
{
    const int which = blockIdx.z;
    const __bf16* W = (which == 0) ? Wq : (which == 1) ? Wk : Wv;
    const int m0 = blockIdx.x * 128;
    const int n0 = blockIdx.y * 128;

    __shared__ __align__(16) __bf16 ldsA[128 * 32];
    __shared__ __align__(16) __bf16 ldsB[128 * 32];

    floatx4 acc[4][4] = {};
    gemm128_core(x, W, m0, n0, ldsA, ldsB, acc);

    const int lane = threadIdx.x & 63;
    const int w    = threadIdx.x >> 6;
    const int quad = lane >> 4;
    const int ln   = lane & 15;
    const int wm   = m0 + ((w >> 1) << 6);
    const int wn   = n0 + ((w & 1) << 6);

    #pragma unroll
    for (int nt = 0; nt < 4; ++nt) {
        const int e = wn + nt * 16 + ln;   // output feature
        const int h = e >> 6;
        const int d = e & 63;
        const float invf = (which < 2)
            ? exp2f(-(float)(d & ~1) * 0.20762050593046014f) : 0.f;
        #pragma unroll
        for (int mt = 0; mt < 4; ++mt) {
            floatx4 c = acc[mt][nt];
            const int mbase = wm + mt * 16 + quad * 4;
            if (which < 2) {
                #pragma unroll
                for (int r = 0; r < 4; ++r) {
                    const int s = (mbase + r) & (SEQ - 1);
                    float self  = c[r];
                    float other = __shfl_xor(self, 1);
                    float sn, cs;
                    sincosf((float)s * invf, &sn, &cs);
                    c[r] = (lane & 1) ? (other * sn + self * cs)
                                      : (self * cs - other * sn);
                }
            }
            const int b = mbase >> 11;
            const int s = mbase & (SEQ - 1);
            const int idx = ((b * NH + h) * SEQ + s) * HD + d;
            #pragma unroll
            for (int r = 0; r < 4; ++r) {
                if (which == 0) {
                    q_ws[idx + r * HD] = (__bf16)c[r];
                } else if (which == 1) {
                    k_out[idx + r * HD] = c[r];
                    k_bf[idx + r * HD]  = (__bf16)c[r];
                } else {
                    v_out[idx + r * HD] = c[r];
                }
            }
            if (which == 2) {
                bf16x4 pk;
                pk[0] = (__bf16)c[0]; pk[1] = (__bf16)c[1];
                pk[2] = (__bf16)c[2]; pk[3] = (__bf16)c[3];
                *(bf16x4*)(vT_ws + ((b * NH + h) * HD + d) * SEQ + s) = pk;
            }
        }
    }
}

// ---------------------------------------------------------------------------
// Kernel 2: causal flash attention (unchanged from R3).
// ---------------------------------------------------------------------------
__global__ __launch_bounds__(256) void attn_kernel(
    const __bf16* __restrict__ q_ws, const __bf16* __restrict__ k_all,
    const __bf16* __restrict__ vT,   __bf16* __restrict__ attn_ws)
{
    const int bh   = blockIdx.x & 31;
    const int qt   = 31 - (blockIdx.x >> 5);
    const int w    = threadIdx.x >> 6;
    const int lane = threadIdx.x & 63;
    const int quad = lane >> 4;
    const int ln   = lane & 15;
    const int r0   = qt * 64 + w * 16;

    const __bf16* qb = q_ws + bh * SEQ * HD;
    const __bf16* kb = k_all + bh * SEQ * HD;
    const __bf16* vb = vT + bh * HD * SEQ;

    const bf16x8 aq0 = *(const bf16x8*)(qb + (r0 + ln) * HD + quad * 8);
    const bf16x8 aq1 = *(const bf16x8*)(qb + (r0 + ln) * HD + 32 + quad * 8);

    floatx4 acc[4] = {};
    float m_i[4] = {-1e30f, -1e30f, -1e30f, -1e30f};
    float l_i[4] = {0.f, 0.f, 0.f, 0.f};

    __shared__ __align__(16) __bf16 ldsp[4][16 * 72];
    __bf16* lp = &ldsp[w][0];

    const __bf16* kbase = kb + ln * HD + quad * 8;
    const __bf16* vbase = vb + ln * SEQ + quad * 8;

    bf16x8 K[8];
    #pragma unroll
    for (int nt = 0; nt < 4; ++nt)
        #pragma unroll
        for (int kc = 0; kc < 2; ++kc)
            K[nt * 2 + kc] = *(const bf16x8*)(kbase + nt * 16 * HD + kc * 32);

    const int nk = qt + 1;
    for (int tk = 0; tk < nk; ++tk) {
        const int j0 = tk << 6;

        bf16x8 V[8];
        #pragma unroll
        for (int nt = 0; nt < 4; ++nt)
            #pragma unroll
            for (int kc = 0; kc < 2; ++kc)
                V[nt * 2 + kc] =
                    *(const bf16x8*)(vbase + nt * 16 * SEQ + j0 + kc * 32);

        floatx4 s[4] = {};
        #pragma unroll
        for (int nt = 0; nt < 4; ++nt) {
            s[nt] = MFMA(aq0, K[nt * 2 + 0], s[nt]);
            s[nt] = MFMA(aq1, K[nt * 2 + 1], s[nt]);
        }

        if (tk + 1 < nk) {
            const __bf16* kn = kbase + (j0 + 64) * HD;
            #pragma unroll
            for (int nt = 0; nt < 4; ++nt)
                #pragma unroll
                for (int kc = 0; kc < 2; ++kc)
                    K[nt * 2 + kc] =
                        *(const bf16x8*)(kn + nt * 16 * HD + kc * 32);
        }

        if (tk == nk - 1) {
            #pragma unroll
            for (int nt = 0; nt < 4; ++nt) {
                const int col = j0 + nt * 16 + ln;
                #pragma unroll
                for (int r = 0; r < 4; ++r)
                    if (col > r0 + quad * 4 + r) s[nt][r] = -1e30f;
            }
        }

        float alpha[4], mnew[4];
        #pragma unroll
        for (int r = 0; r < 4; ++r) {
            float v = fmaxf(fmaxf(s[0][r], s[1][r]), fmaxf(s[2][r], s[3][r]));
            v = fmaxf(v, __shfl_xor(v, 1));
            v = fmaxf(v, __shfl_xor(v, 2));
            v = fmaxf(v, __shfl_xor(v, 4));
            v = fmaxf(v, __shfl_xor(v, 8));
            const float mn = fmaxf(m_i[r], v * 0.125f);
            alpha[r] = __expf(m_i[r] - mn);
            m_i[r] = mn;
            mnew[r] = mn;
        }
        floatx4 p[4];
        #pragma unroll
        for (int nt = 0; nt < 4; ++nt)
            #pragma unroll
            for (int r = 0; r < 4; ++r)
                p[nt][r] = __expf(fmaf(s[nt][r], 0.125f, -mnew[r]));
        #pragma unroll
        for (int r = 0; r < 4; ++r) {
            float v = (p[0][r] + p[1][r]) + (p[2][r] + p[3][r]);
            v += __shfl_xor(v, 1);
            v += __shfl_xor(v, 2);
            v += __shfl_xor(v, 4);
            v += __shfl_xor(v, 8);
            l_i[r] = l_i[r] * alpha[r] + v;
        }
        #pragma unroll
        for (int nt = 0; nt < 4; ++nt)
            #pragma unroll
            for (int r = 0; r < 4; ++r)
                acc[nt][r] *= alpha[r];

        #pragma unroll
        for (int nt = 0; nt < 4; ++nt)
            #pragma unroll
            for (int r = 0; r < 4; ++r)
                lp[(quad * 4 + r) * 72 + nt * 16 + ln] = (__bf16)p[nt][r];
        const bf16x8 ap0 = *(const bf16x8*)(lp + ln * 72 + quad * 8);
        const bf16x8 ap1 = *(const bf16x8*)(lp + ln * 72 + 32 + quad * 8);

        #pragma unroll
        for (int nt = 0; nt < 4; ++nt) {
            acc[nt] = MFMA(ap0, V[nt * 2 + 0], acc[nt]);
            acc[nt] = MFMA(ap1, V[nt * 2 + 1], acc[nt]);
        }
    }

    const int b = bh >> 4, h = bh & 15;
    #pragma unroll
    for (int r = 0; r < 4; ++r) {
        const float inv = 1.f / fmaxf(l_i[r], 1e-30f);
        const int s = r0 + quad * 4 + r;
        #pragma unroll
        for (int nt = 0; nt < 4; ++nt) {
            attn_ws[(b * SEQ + s) * D_MODEL + h * HD + nt * 16 + ln] =
                (__bf16)(acc[nt][r] * inv);
        }
    }
}

// ---------------------------------------------------------------------------
// Kernel 3: output projection  out = attn * Wo^T  (f32 out), m97-style core.
// ---------------------------------------------------------------------------
__global__ __launch_bounds__(256) void out_proj_kernel(
    const __bf16* __restrict__ A, const __bf16* __restrict__ Wo,
    float* __restrict__ out)
{
    const int m0 = blockIdx.x * 128;
    const int n0 = blockIdx.y * 128;

    __shared__ __align__(16) __bf16 ldsA[128 * 32];
    __shared__ __align__(16) __bf16 ldsB[128 * 32];

    floatx4 acc[4][4] = {};
    gemm128_core(A, Wo, m0, n0, ldsA, ldsB, acc);

    const int lane = threadIdx.x & 63;
    const int w    = threadIdx.x >> 6;
    const int quad = lane >> 4;
    const int ln   = lane & 15;
    const int wm   = m0 + ((w >> 1) << 6);
    const int wn   = n0 + ((w & 1) << 6);

    #pragma unroll
    for (int mt = 0; mt < 4; ++mt) {
        #pragma unroll
        for (int nt = 0; nt < 4; ++nt) {
            const floatx4 c = acc[mt][nt];
            const int e = wn + nt * 16 + ln;
            const int mbase = wm + mt * 16 + quad * 4;
            #pragma unroll
            for (int r = 0; r < 4; ++r)
                out[(mbase + r) * D_MODEL + e] = c[r];
        }
    }
}

// ---------------------------------------------------------------------------
extern "C" void kernel_launch(void* const* d_in, const int* in_sizes, int n_in,
                              void* d_out, int out_size, void* d_ws, size_t ws_size,
                              hipStream_t stream)
{
    (void)in_sizes; (void)n_in; (void)out_size; (void)ws_size;
    const float* x  = (const float*)d_in[0];
    // d_in[1] = mask — analytic causal mask, not read
    const float* Wq = (const float*)d_in[2];
    const float* Wk = (const float*)d_in[3];
    const float* Wv = (const float*)d_in[4];
    const float* Wo = (const float*)d_in[5];

    float* out   = (float*)d_out;           // [B,S,D]
    float* k_out = out + XN;                // [B,H,S,hd]
    float* v_out = k_out + XN;              // [B,H,S,hd]

    __bf16* ws      = (__bf16*)d_ws;
    __bf16* x_bf    = ws;                   // XN
    __bf16* Wq_bf   = ws + XN;              // WN
    __bf16* Wk_bf   = Wq_bf + WN;
    __bf16* Wv_bf   = Wk_bf + WN;
    __bf16* Wo_bf   = Wv_bf + WN;
    __bf16* q_ws    = Wo_bf + WN;           // XN  [B,H,S,hd]
    __bf16* k_bf    = q_ws + XN;            // XN  [B,H,S,hd]
    __bf16* vT_ws   = k_bf + XN;            // XN  [B,H,hd,S]
    __bf16* attn_ws = vT_ws + XN;           // XN  [B,S,D]

    dim3 gc(XN / 4 / 256, 5);
    cvt_kernel<<<gc, 256, 0, stream>>>(x, Wq, Wk, Wv, Wo, ws);

    dim3 g1(MROWS / 128, D_MODEL / 128, 3);
    qkv_rope_kernel<<<g1, 256, 0, stream>>>(x_bf, Wq_bf, Wk_bf, Wv_bf,
                                            q_ws, k_bf, vT_ws, k_out, v_out);

    attn_kernel<<<dim3(32 * 32), 256, 0, stream>>>(q_ws, k_bf, vT_ws, attn_ws);

    dim3 g3(MROWS / 128, D_MODEL / 128);
    out_proj_kernel<<<g3, 256, 0, stream>>>(attn_ws, Wo_bf, out);
}